// Round 20
// baseline (146.887 us; speedup 1.0000x reference)
//
#include <hip/hip_runtime.h>
#include <math.h>

#define C      128
#define C2U    64         // uints (2x bf16) per row
#define BSH    7          // 128 nodes per coarse bucket
#define BNODES 128
#define CHUNKE 6144       // edges per coarse block (261 blocks -> full CU coverage)
#define PADMAX (BNODES * 3)   // max pad per bucket (3 per node)
#define BSLOT  3072       // fixed pk slots per bucket (mean 2046, +11 sigma safe)
#define GSTRIDE 16        // gcur line padding (one counter per 64B line)

typedef __attribute__((ext_vector_type(8))) short bf16x8;   // 8 bf16 = 4 VGPR
typedef __attribute__((ext_vector_type(4))) float f32x4;

union UV { uint4 u; bf16x8 h; };

// ---- bf16 helpers (manual RNE) ----
__device__ __forceinline__ unsigned int f2bf(float f) {
    unsigned int u = __float_as_uint(f);
    return (u + 0x7fffu + ((u >> 16) & 1u)) >> 16;
}
__device__ __forceinline__ float bflo(unsigned int v) { return __uint_as_float(v << 16); }
__device__ __forceinline__ float bfhi(unsigned int v) { return __uint_as_float(v & 0xffff0000u); }

// ---- cscat2: fused hist + global reserve + scatter; last block does W^T + sentinel ----
__global__ __launch_bounds__(256) void ngl_cscat2_kernel(
        const int* __restrict__ src, const int* __restrict__ dst, int E,
        int NBUCK, int NBLK, int* __restrict__ gcur, unsigned int* __restrict__ pk,
        const float* __restrict__ W, unsigned int* __restrict__ Wt,
        uint4* __restrict__ hh4, int N) {
    int blk = blockIdx.x;
    if (blk == NBLK) {                       // service block: W -> W^T bf16, hh sentinel
        for (int i = threadIdx.x; i < C * C2U; i += 256) {
            int col = i >> 6, k2 = i & 63;
            float w0 = W[(2 * k2) * C + col];
            float w1 = W[(2 * k2 + 1) * C + col];
            Wt[col * C2U + k2] = f2bf(w0) | (f2bf(w1) << 16);
        }
        if (threadIdx.x < 16)
            hh4[(long long)N * 16 + threadIdx.x] = make_uint4(0, 0, 0, 0);
        return;
    }
    extern __shared__ int sh[];              // [NBUCK]: hist, then in-bucket cursors
    for (int i = threadIdx.x; i < NBUCK; i += 256) sh[i] = 0;
    __syncthreads();
    int base = blk * CHUNKE;
    int end = base + CHUNKE; if (end > E) end = E;
    for (int i = base + threadIdx.x; i < end; i += 256)
        atomicAdd(&sh[dst[i] >> BSH], 1);
    __syncthreads();
    // reserve a contiguous range in each bucket region
    for (int i = threadIdx.x; i < NBUCK; i += 256) {
        int c = sh[i];
        sh[i] = (c > 0) ? atomicAdd(&gcur[i * GSTRIDE], c) : 0;
    }
    __syncthreads();
    for (int i = base + threadIdx.x; i < end; i += 256) {
        int d = dst[i];
        int b = d >> BSH;
        int pos = atomicAdd(&sh[b], 1);      // LDS cursor within reserved range
        pk[(long long)b * BSLOT + pos] =
            (unsigned int)src[i] | ((unsigned int)(d & (BNODES - 1)) << 17);
    }
}

// ---- fcomb: bucketbase by reduction over gcur; per-bucket hist -> deg/dis/offset
//      + PADDED fine scatter (src only) ----
__global__ __launch_bounds__(256) void ngl_fcomb_kernel(
        const unsigned int* __restrict__ pk, const int* __restrict__ gcur,
        int NBUCK, int E, int N,
        int* __restrict__ deg, float* __restrict__ dis,
        int* __restrict__ offset, int* __restrict__ payload) {
    __shared__ int red[256];
    __shared__ int h[BNODES];
    __shared__ int sc[BNODES];
    __shared__ int cur[BNODES];
    int b = blockIdx.x;
    int t = threadIdx.x;

    // unpadded bucket base = sum of totals of buckets < b
    int partial = 0;
    for (int i = t; i < b; i += 256) partial += gcur[i * GSTRIDE];
    red[t] = partial;
    __syncthreads();
    for (int o = 128; o > 0; o >>= 1) {
        if (t < o) red[t] += red[t + o];
        __syncthreads();
    }
    int s = red[0];
    int cnt_b = gcur[b * GSTRIDE];
    int pbase = s + b * PADMAX;
    const unsigned int* mypk = pk + (long long)b * BSLOT;

    if (t < BNODES) h[t] = 0;
    __syncthreads();
    for (int i = t; i < cnt_b; i += 256)
        atomicAdd(&h[mypk[i] >> 17], 1);
    __syncthreads();
    if (t < BNODES) sc[t] = (h[t] + 3) & ~3;       // padded counts
    __syncthreads();
    for (int o = 1; o < BNODES; o <<= 1) {
        int v = 0;
        if (t < BNODES && t >= o) v = sc[t - o];
        __syncthreads();
        if (t < BNODES && t >= o) sc[t] += v;
        __syncthreads();
    }
    if (t < BNODES) {
        int pc = (h[t] + 3) & ~3;
        int ex = sc[t] - pc;                        // exclusive padded scan
        cur[t] = ex;
        int n = b * BNODES + t;
        if (n < N) {
            int dv = h[t];
            deg[n] = dv;
            dis[n] = rsqrtf((float)(dv + 1));
            offset[n] = pbase + ex;
        }
    }
    __syncthreads();
    for (int i = t; i < cnt_b; i += 256) {
        unsigned int p = mypk[i];
        int loc = (int)(p >> 17);
        int pos = pbase + atomicAdd(&cur[loc], 1);
        payload[pos] = (int)(p & 0x1FFFFu);
    }
    __syncthreads();
    if (t < BNODES) {
        for (int j = cur[t]; j < sc[t]; ++j)        // pad with sentinel N
            payload[pbase + j] = N;
    }
}

// ---------------- MFMA GEMM-first: hh = bf16( (x*dis) @ W ) ----------------
__global__ __launch_bounds__(256, 2) void ngl_gemmcvt_kernel(
        const float4* __restrict__ x4, const float* __restrict__ dis,
        const uint4* __restrict__ wt4,
        unsigned short* __restrict__ hh, int N, int tiles_total) {
    int wid  = threadIdx.x >> 6;
    int lane = threadIdx.x & 63;
    int r  = lane & 15;       // row-in-tile (A) / col-in-tile (B,D)
    int kg = lane >> 4;       // k-group 0..3

    bf16x8 bfr[8][4];
    #pragma unroll
    for (int nt = 0; nt < 8; ++nt) {
        #pragma unroll
        for (int kk = 0; kk < 4; ++kk) {
            UV u; u.u = wt4[(nt * 16 + r) * 16 + kk * 4 + kg];
            bfr[nt][kk] = u.h;
        }
    }

    for (int tile = blockIdx.x * 4 + wid; tile < tiles_total; tile += gridDim.x * 4) {
        int row0 = tile * 16;
        int arow = row0 + r;
        float d = (arow < N) ? dis[arow] : 0.f;

        bf16x8 afr[4];
        #pragma unroll
        for (int kk = 0; kk < 4; ++kk) {
            float4 a = make_float4(0, 0, 0, 0), bb = make_float4(0, 0, 0, 0);
            if (arow < N) {
                a  = x4[(long long)arow * 32 + kk * 8 + kg * 2];
                bb = x4[(long long)arow * 32 + kk * 8 + kg * 2 + 1];
            }
            UV u;
            u.u.x = f2bf(a.x * d) | (f2bf(a.y * d) << 16);
            u.u.y = f2bf(a.z * d) | (f2bf(a.w * d) << 16);
            u.u.z = f2bf(bb.x * d) | (f2bf(bb.y * d) << 16);
            u.u.w = f2bf(bb.z * d) | (f2bf(bb.w * d) << 16);
            afr[kk] = u.h;
        }

        f32x4 acc[8];
        #pragma unroll
        for (int nt = 0; nt < 8; ++nt) acc[nt] = (f32x4){0.f, 0.f, 0.f, 0.f};

        #pragma unroll
        for (int kk = 0; kk < 4; ++kk) {
            #pragma unroll
            for (int nt = 0; nt < 8; ++nt) {
                acc[nt] = __builtin_amdgcn_mfma_f32_16x16x32_bf16(
                    afr[kk], bfr[nt][kk], acc[nt], 0, 0, 0);
            }
        }

        #pragma unroll
        for (int nt = 0; nt < 8; ++nt) {
            #pragma unroll
            for (int j = 0; j < 4; ++j) {
                int rr = row0 + kg * 4 + j;
                if (rr < N)
                    hh[(long long)rr * C + nt * 16 + r] =
                        (unsigned short)f2bf(acc[nt][j]);
            }
        }
    }
}

__device__ __forceinline__ float silu1(float v) {
    return v / (1.0f + __expf(-v));
}

// one wave per node; 4-deep pipeline; padded lists -> NO remainder tail.
// out[n] = silu( dis[n] * (hh[n] + sum_edges hh[src]) + b )   (fp32 write)
__global__ __launch_bounds__(256) void ngl_gather_kernel(
        const unsigned int* __restrict__ hh, const float* __restrict__ dis,
        const int* __restrict__ offset, const int* __restrict__ deg,
        const int* __restrict__ payload, const float* __restrict__ bias,
        float* __restrict__ out, int N) {
    int node = blockIdx.x * 4 + (threadIdx.x >> 6);
    int lane = threadIdx.x & 63;
    if (node >= N) return;

    unsigned int sv = hh[(unsigned int)(node * C2U + lane)];
    float accx = bflo(sv);
    float accy = bfhi(sv);

    int beg = offset[node];
    int cntp = (deg[node] + 3) & ~3;    // padded count (multiple of 4)

    if (cntp > 0) {
        int e0 = payload[beg + 0], e1 = payload[beg + 1];
        int e2 = payload[beg + 2], e3 = payload[beg + 3];
        int i = 0;
        while (true) {
            int c0 = e0, c1 = e1, c2 = e2, c3 = e3;
            int nb = beg + i + 4;
            if (i + 8 <= cntp) {                // prefetch next payload group
                e0 = payload[nb + 0]; e1 = payload[nb + 1];
                e2 = payload[nb + 2]; e3 = payload[nb + 3];
            }
            unsigned int v0 = hh[(unsigned int)(c0 * C2U + lane)];
            unsigned int v1 = hh[(unsigned int)(c1 * C2U + lane)];
            unsigned int v2 = hh[(unsigned int)(c2 * C2U + lane)];
            unsigned int v3 = hh[(unsigned int)(c3 * C2U + lane)];
            accx += bflo(v0); accy += bfhi(v0);
            accx += bflo(v1); accy += bfhi(v1);
            accx += bflo(v2); accy += bfhi(v2);
            accx += bflo(v3); accy += bfhi(v3);
            i += 4;
            if (i >= cntp) break;
        }
    }
    float dn = dis[node];
    float2 bb = ((const float2*)bias)[lane];
    float ox = silu1(accx * dn + bb.x);
    float oy = silu1(accy * dn + bb.y);
    __builtin_nontemporal_store(ox, &out[(unsigned int)(node * C + 2 * lane)]);
    __builtin_nontemporal_store(oy, &out[(unsigned int)(node * C + 2 * lane + 1)]);
}

extern "C" void kernel_launch(void* const* d_in, const int* in_sizes, int n_in,
                              void* d_out, int out_size, void* d_ws, size_t ws_size,
                              hipStream_t stream) {
    const float* x = (const float*)d_in[0];
    const int*   ei = (const int*)d_in[1];
    const float* W = (const float*)d_in[2];
    const float* b = (const float*)d_in[3];

    int N = in_sizes[0] / C;
    int E = in_sizes[1] / 2;
    const int* src = ei;
    const int* dst = ei + E;

    int NBUCK = (N + BNODES - 1) / BNODES;        // 782
    int NBLK  = (E + CHUNKE - 1) / CHUNKE;        // 261

    char* ws = (char*)d_ws;
    size_t off = 0;
    unsigned short* hh = (unsigned short*)(ws + off); off += (size_t)(N + 1) * C * 2; // 25.6 MB (+zero row)
    unsigned int* pk = (unsigned int*)(ws + off);  off += (size_t)NBUCK * BSLOT * 4;  // 9.6 MB
    int* payload = (int*)(ws + off);               off += ((size_t)E + (size_t)NBUCK * PADMAX + 1024) * 4;
    int* gcur = (int*)(ws + off);                  off += (size_t)NBUCK * GSTRIDE * 4;
    int* deg = (int*)(ws + off);                   off += (size_t)N * 4;
    int* offset = (int*)(ws + off);                off += (size_t)N * 4;
    float* dis = (float*)(ws + off);               off += (size_t)N * 4;
    unsigned int* Wt = (unsigned int*)(ws + off);  off += (size_t)C * C2U * 4;

    (void)hipMemsetAsync(gcur, 0, (size_t)NBUCK * GSTRIDE * 4, stream);

    ngl_cscat2_kernel<<<NBLK + 1, 256, NBUCK * 4, stream>>>(
        src, dst, E, NBUCK, NBLK, gcur, pk, W, Wt, (uint4*)hh, N);
    ngl_fcomb_kernel<<<NBUCK, 256, 0, stream>>>(pk, gcur, NBUCK, E, N,
                                                deg, dis, offset, payload);

    int tiles = (N + 15) / 16;            // 6250
    ngl_gemmcvt_kernel<<<512, 256, 0, stream>>>(
        (const float4*)x, dis, (const uint4*)Wt, hh, N, tiles);

    ngl_gather_kernel<<<(N + 3) / 4, 256, 0, stream>>>(
        (const unsigned int*)hh, dis, offset, deg, payload, b, (float*)d_out, N);
}

// Round 21
// 143.639 us; speedup vs baseline: 1.0226x; 1.0226x over previous
//
#include <hip/hip_runtime.h>
#include <math.h>

#define C      128
#define C2U    64         // uints (2x bf16) per row
#define BSH    7          // 128 nodes per coarse bucket
#define BNODES 128
#define CHUNKE 6144       // edges per coarse block (261 blocks -> full CU coverage)
#define PADMAX (BNODES * 3)   // max pad per bucket (3 per node)

typedef __attribute__((ext_vector_type(8))) short bf16x8;   // 8 bf16 = 4 VGPR
typedef __attribute__((ext_vector_type(4))) float f32x4;

union UV { uint4 u; bf16x8 h; };

// ---- bf16 helpers (manual RNE) ----
__device__ __forceinline__ unsigned int f2bf(float f) {
    unsigned int u = __float_as_uint(f);
    return (u + 0x7fffu + ((u >> 16) & 1u)) >> 16;
}
__device__ __forceinline__ float bflo(unsigned int v) { return __uint_as_float(v << 16); }
__device__ __forceinline__ float bfhi(unsigned int v) { return __uint_as_float(v & 0xffff0000u); }

// ---------------- a1: coarse histogram (LDS atomics only) ----------------
__global__ __launch_bounds__(256) void ngl_chist_kernel(
        const int* __restrict__ dst, int E, int NBUCK, int NBLK, int* __restrict__ cnt) {
    extern __shared__ int h[];
    for (int i = threadIdx.x; i < NBUCK; i += 256) h[i] = 0;
    __syncthreads();
    int base = blockIdx.x * CHUNKE;
    int end = base + CHUNKE; if (end > E) end = E;
    for (int i = base + threadIdx.x; i < end; i += 256)
        atomicAdd(&h[dst[i] >> BSH], 1);
    __syncthreads();
    for (int i = threadIdx.x; i < NBUCK; i += 256)
        cnt[i * NBLK + blockIdx.x] = h[i];
}

// ---------------- a2a: partial sums; hosts W->W^T bf16 + hh sentinel row ----------------
__global__ __launch_bounds__(256) void ngl_s1_kernel(const int* __restrict__ in,
                                                     int* __restrict__ bsum, int M,
                                                     const float* __restrict__ W,
                                                     unsigned int* __restrict__ Wt,
                                                     uint4* __restrict__ hh4, int N) {
    int g = blockIdx.x * 256 + threadIdx.x;
    if (g < C * C2U) {
        int col = g >> 6, k2 = g & 63;
        float w0 = W[(2 * k2) * C + col];
        float w1 = W[(2 * k2 + 1) * C + col];
        Wt[col * C2U + k2] = f2bf(w0) | (f2bf(w1) << 16);
    }
    if (blockIdx.x == 0 && threadIdx.x < 16)          // sentinel zero row N of hh
        hh4[(long long)N * 16 + threadIdx.x] = make_uint4(0, 0, 0, 0);

    __shared__ int red[256];
    int t = threadIdx.x;
    int base = blockIdx.x * 1024 + t * 4;
    int s = 0;
    #pragma unroll
    for (int j = 0; j < 4; ++j) {
        int i = base + j;
        if (i < M) s += in[i];
    }
    red[t] = s;
    __syncthreads();
    for (int o = 128; o > 0; o >>= 1) {
        if (t < o) red[t] += red[t + o];
        __syncthreads();
    }
    if (t == 0) bsum[blockIdx.x] = red[0];
}

// ---------------- a2b: exclusive scan (redundant block-sum scan in LDS) ----------------
__global__ __launch_bounds__(256) void ngl_s2_kernel(
        const int* __restrict__ in, const int* __restrict__ bsum,
        int* __restrict__ out, int M, int NB) {
    __shared__ int pre[256];
    __shared__ int red[256];
    int t = threadIdx.x;
    pre[t] = (t < NB) ? bsum[t] : 0;
    __syncthreads();
    for (int o = 1; o < 256; o <<= 1) {
        int v = 0;
        if (t >= o) v = pre[t - o];
        __syncthreads();
        if (t >= o) pre[t] += v;
        __syncthreads();
    }
    int boff = (blockIdx.x == 0) ? 0 : pre[blockIdx.x - 1];

    int base = blockIdx.x * 1024 + t * 4;
    int v[4];
    int s = 0;
    #pragma unroll
    for (int j = 0; j < 4; ++j) {
        int i = base + j;
        v[j] = (i < M) ? in[i] : 0;
        s += v[j];
    }
    red[t] = s;
    __syncthreads();
    for (int o = 1; o < 256; o <<= 1) {
        int u = 0;
        if (t >= o) u = red[t - o];
        __syncthreads();
        if (t >= o) red[t] += u;
        __syncthreads();
    }
    int run = boff + ((t == 0) ? 0 : red[t - 1]);
    #pragma unroll
    for (int j = 0; j < 4; ++j) {
        int i = base + j;
        if (i < M) {
            out[i] = run;
            run += v[j];
        }
    }
}

// ---------------- a3: coarse scatter; pk = src | dstloc<<17 ----------------
__global__ __launch_bounds__(256) void ngl_cscat_kernel(
        const int* __restrict__ src, const int* __restrict__ dst, int E,
        int NBUCK, int NBLK, const int* __restrict__ cntoff,
        unsigned int* __restrict__ pk) {
    extern __shared__ int cur[];
    int blk = blockIdx.x;
    for (int i = threadIdx.x; i < NBUCK; i += 256) cur[i] = cntoff[i * NBLK + blk];
    __syncthreads();
    int base = blk * CHUNKE;
    int end = base + CHUNKE; if (end > E) end = E;
    for (int i = base + threadIdx.x; i < end; i += 256) {
        int d = dst[i];
        int b = d >> BSH;
        int pos = atomicAdd(&cur[b], 1);
        pk[pos] = (unsigned int)src[i] | ((unsigned int)(d & (BNODES - 1)) << 17);
    }
}

// ---- f: per-bucket hist -> deg/dis/offset + PADDED fine scatter (src only) ----
__global__ __launch_bounds__(256) void ngl_fcomb_kernel(
        const unsigned int* __restrict__ pk, const int* __restrict__ cntoff,
        int NBLK, int E, int N,
        int* __restrict__ deg, float* __restrict__ dis,
        int* __restrict__ offset, int* __restrict__ payload) {
    __shared__ int h[BNODES];
    __shared__ int sc[BNODES];
    __shared__ int cur[BNODES];
    int b = blockIdx.x, nb = gridDim.x;
    int s = cntoff[b * NBLK];
    int e = (b + 1 < nb) ? cntoff[(b + 1) * NBLK] : E;
    int pbase = s + b * PADMAX;
    int t = threadIdx.x;
    if (t < BNODES) h[t] = 0;
    __syncthreads();
    for (int i = s + t; i < e; i += 256)
        atomicAdd(&h[pk[i] >> 17], 1);
    __syncthreads();
    if (t < BNODES) sc[t] = (h[t] + 3) & ~3;       // padded counts
    __syncthreads();
    for (int o = 1; o < BNODES; o <<= 1) {
        int v = 0;
        if (t < BNODES && t >= o) v = sc[t - o];
        __syncthreads();
        if (t < BNODES && t >= o) sc[t] += v;
        __syncthreads();
    }
    if (t < BNODES) {
        int pc = (h[t] + 3) & ~3;
        int ex = sc[t] - pc;                        // exclusive padded scan
        cur[t] = ex;
        int n = b * BNODES + t;
        if (n < N) {
            int dv = h[t];
            deg[n] = dv;
            dis[n] = rsqrtf((float)(dv + 1));
            offset[n] = pbase + ex;
        }
    }
    __syncthreads();
    for (int i = s + t; i < e; i += 256) {
        unsigned int p = pk[i];
        int loc = (int)(p >> 17);
        int pos = pbase + atomicAdd(&cur[loc], 1);
        payload[pos] = (int)(p & 0x1FFFFu);
    }
    __syncthreads();
    if (t < BNODES) {
        for (int j = cur[t]; j < sc[t]; ++j)        // pad with sentinel N
            payload[pbase + j] = N;
    }
}

// ---------------- MFMA GEMM-first: hh = bf16( (x*dis) @ W ) ----------------
// A fragments built in-register from fp32 x rows scaled by dis (replaces cvtx).
__global__ __launch_bounds__(256, 2) void ngl_gemmcvt_kernel(
        const float4* __restrict__ x4, const float* __restrict__ dis,
        const uint4* __restrict__ wt4,
        unsigned short* __restrict__ hh, int N, int tiles_total) {
    int wid  = threadIdx.x >> 6;
    int lane = threadIdx.x & 63;
    int r  = lane & 15;       // row-in-tile (A) / col-in-tile (B,D)
    int kg = lane >> 4;       // k-group 0..3

    bf16x8 bfr[8][4];
    #pragma unroll
    for (int nt = 0; nt < 8; ++nt) {
        #pragma unroll
        for (int kk = 0; kk < 4; ++kk) {
            UV u; u.u = wt4[(nt * 16 + r) * 16 + kk * 4 + kg];
            bfr[nt][kk] = u.h;
        }
    }

    for (int tile = blockIdx.x * 4 + wid; tile < tiles_total; tile += gridDim.x * 4) {
        int row0 = tile * 16;
        int arow = row0 + r;
        float d = (arow < N) ? dis[arow] : 0.f;

        bf16x8 afr[4];
        #pragma unroll
        for (int kk = 0; kk < 4; ++kk) {
            float4 a = make_float4(0, 0, 0, 0), bb = make_float4(0, 0, 0, 0);
            if (arow < N) {
                a  = x4[(long long)arow * 32 + kk * 8 + kg * 2];
                bb = x4[(long long)arow * 32 + kk * 8 + kg * 2 + 1];
            }
            UV u;
            u.u.x = f2bf(a.x * d) | (f2bf(a.y * d) << 16);
            u.u.y = f2bf(a.z * d) | (f2bf(a.w * d) << 16);
            u.u.z = f2bf(bb.x * d) | (f2bf(bb.y * d) << 16);
            u.u.w = f2bf(bb.z * d) | (f2bf(bb.w * d) << 16);
            afr[kk] = u.h;
        }

        f32x4 acc[8];
        #pragma unroll
        for (int nt = 0; nt < 8; ++nt) acc[nt] = (f32x4){0.f, 0.f, 0.f, 0.f};

        #pragma unroll
        for (int kk = 0; kk < 4; ++kk) {
            #pragma unroll
            for (int nt = 0; nt < 8; ++nt) {
                acc[nt] = __builtin_amdgcn_mfma_f32_16x16x32_bf16(
                    afr[kk], bfr[nt][kk], acc[nt], 0, 0, 0);
            }
        }

        // D: row = row0 + kg*4 + j, col = nt*16 + r; store bf16
        #pragma unroll
        for (int nt = 0; nt < 8; ++nt) {
            #pragma unroll
            for (int j = 0; j < 4; ++j) {
                int rr = row0 + kg * 4 + j;
                if (rr < N)
                    hh[(long long)rr * C + nt * 16 + r] =
                        (unsigned short)f2bf(acc[nt][j]);
            }
        }
    }
}

__device__ __forceinline__ float silu1(float v) {
    return v / (1.0f + __expf(-v));
}

// one wave per node; 4-deep pipeline; padded lists -> NO remainder tail.
// out[n] = silu( dis[n] * (hh[n] + sum_edges hh[src]) + b )   (fp32 write)
__global__ __launch_bounds__(256) void ngl_gather_kernel(
        const unsigned int* __restrict__ hh, const float* __restrict__ dis,
        const int* __restrict__ offset, const int* __restrict__ deg,
        const int* __restrict__ payload, const float* __restrict__ bias,
        float* __restrict__ out, int N) {
    int node = blockIdx.x * 4 + (threadIdx.x >> 6);
    int lane = threadIdx.x & 63;
    if (node >= N) return;

    unsigned int sv = hh[(unsigned int)(node * C2U + lane)];
    float accx = bflo(sv);
    float accy = bfhi(sv);

    int beg = offset[node];
    int cntp = (deg[node] + 3) & ~3;    // padded count (multiple of 4)

    if (cntp > 0) {
        int e0 = payload[beg + 0], e1 = payload[beg + 1];
        int e2 = payload[beg + 2], e3 = payload[beg + 3];
        int i = 0;
        while (true) {
            int c0 = e0, c1 = e1, c2 = e2, c3 = e3;
            int nb = beg + i + 4;
            if (i + 8 <= cntp) {                // prefetch next payload group
                e0 = payload[nb + 0]; e1 = payload[nb + 1];
                e2 = payload[nb + 2]; e3 = payload[nb + 3];
            }
            unsigned int v0 = hh[(unsigned int)(c0 * C2U + lane)];
            unsigned int v1 = hh[(unsigned int)(c1 * C2U + lane)];
            unsigned int v2 = hh[(unsigned int)(c2 * C2U + lane)];
            unsigned int v3 = hh[(unsigned int)(c3 * C2U + lane)];
            accx += bflo(v0); accy += bfhi(v0);
            accx += bflo(v1); accy += bfhi(v1);
            accx += bflo(v2); accy += bfhi(v2);
            accx += bflo(v3); accy += bfhi(v3);
            i += 4;
            if (i >= cntp) break;
        }
    }
    float dn = dis[node];
    float2 bb = ((const float2*)bias)[lane];
    float ox = silu1(accx * dn + bb.x);
    float oy = silu1(accy * dn + bb.y);
    __builtin_nontemporal_store(ox, &out[(unsigned int)(node * C + 2 * lane)]);
    __builtin_nontemporal_store(oy, &out[(unsigned int)(node * C + 2 * lane + 1)]);
}

extern "C" void kernel_launch(void* const* d_in, const int* in_sizes, int n_in,
                              void* d_out, int out_size, void* d_ws, size_t ws_size,
                              hipStream_t stream) {
    const float* x = (const float*)d_in[0];
    const int*   ei = (const int*)d_in[1];
    const float* W = (const float*)d_in[2];
    const float* b = (const float*)d_in[3];

    int N = in_sizes[0] / C;
    int E = in_sizes[1] / 2;
    const int* src = ei;
    const int* dst = ei + E;

    int NBUCK = (N + BNODES - 1) / BNODES;        // 782
    int NBLK  = (E + CHUNKE - 1) / CHUNKE;        // 261
    int M     = NBUCK * NBLK;                     // ~204k
    int NB2   = (M + 1023) / 1024;                // ~200 (<=256 required)

    char* ws = (char*)d_ws;
    size_t off = 0;
    unsigned short* hh = (unsigned short*)(ws + off); off += (size_t)(N + 1) * C * 2; // 25.6 MB (+zero row)
    unsigned int* pk = (unsigned int*)(ws + off);  off += (size_t)E * 4;              // 6.4 MB
    int* payload = (int*)(ws + off);               off += ((size_t)E + (size_t)NBUCK * PADMAX + 1024) * 4;
    int* cnt = (int*)(ws + off);                   off += (size_t)M * 4;
    int* cntoff = (int*)(ws + off);                off += (size_t)M * 4;
    int* s1sum = (int*)(ws + off);                 off += 1024 * 4;
    int* deg = (int*)(ws + off);                   off += (size_t)N * 4;
    int* offset = (int*)(ws + off);                off += (size_t)N * 4;
    float* dis = (float*)(ws + off);               off += (size_t)N * 4;
    unsigned int* Wt = (unsigned int*)(ws + off);  off += (size_t)C * C2U * 4;

    ngl_chist_kernel<<<NBLK, 256, NBUCK * 4, stream>>>(dst, E, NBUCK, NBLK, cnt);
    ngl_s1_kernel<<<NB2, 256, 0, stream>>>(cnt, s1sum, M, W, Wt, (uint4*)hh, N);
    ngl_s2_kernel<<<NB2, 256, 0, stream>>>(cnt, s1sum, cntoff, M, NB2);
    ngl_cscat_kernel<<<NBLK, 256, NBUCK * 4, stream>>>(src, dst, E, NBUCK, NBLK, cntoff, pk);
    ngl_fcomb_kernel<<<NBUCK, 256, 0, stream>>>(pk, cntoff, NBLK, E, N,
                                                deg, dis, offset, payload);

    int tiles = (N + 15) / 16;            // 6250
    ngl_gemmcvt_kernel<<<512, 256, 0, stream>>>(
        (const float4*)x, dis, (const uint4*)Wt, hh, N, tiles);

    ngl_gather_kernel<<<(N + 3) / 4, 256, 0, stream>>>(
        (const unsigned int*)hh, dis, offset, deg, payload, b, (float*)d_out, N);
}